// Round 1
// baseline (243.418 us; speedup 1.0000x reference)
//
#include <hip/hip_runtime.h>

// SSIM (win=7, valid) fused single-pass kernel for (32,3,512,512) fp32 inputs.
// 96 images of 512x512 -> mean over 96x506x506 S map.
//
// Per block: one image x one 46-row output strip, 128 threads x 4 cols = 512 cols.
// Vertical running window sums in registers, horizontal 7-sum via LDS halo.

namespace {
constexpr int W      = 512;
constexpr int HH     = 512;
constexpr int NIMG   = 96;
constexpr int OW     = 506;
constexpr int RSTRIP = 46;   // 11 * 46 = 506 output rows exactly
constexpr int NSTRIP = 11;
constexpr float C1f   = 1.0e-4f;           // (0.01*1.0)^2
constexpr float C2f   = 9.0e-4f;           // (0.03*1.0)^2
constexpr float COVN  = 49.0f / 48.0f;     // NP/(NP-1)
constexpr float INV49 = 1.0f / 49.0f;
constexpr double NPIX = 96.0 * 506.0 * 506.0;  // 24,579,456
constexpr int LSTRIDE = 520;               // plane stride: 512 + 8 halo slack
}

__global__ __launch_bounds__(128) void ssim_main(const float* __restrict__ X,
                                                 const float* __restrict__ Y,
                                                 double* __restrict__ acc)
{
    __shared__ float ldsV[5 * LSTRIDE];
    __shared__ float wsum[2];

    const int t   = threadIdx.x;
    const int c   = t * 4;                    // first of this thread's 4 columns
    const int img = blockIdx.y;
    const int r0  = blockIdx.x * RSTRIP;      // first output row of strip

    const float* xb = X + (size_t)img * W * HH;
    const float* yb = Y + (size_t)img * W * HH;

    // running vertical sums over the 7-row window, per column:
    // V[0]=sum x, V[1]=sum y, V[2]=sum x^2, V[3]=sum y^2, V[4]=sum x*y
    float V[5][4];
#pragma unroll
    for (int q = 0; q < 5; q++)
#pragma unroll
        for (int i = 0; i < 4; i++) V[q][i] = 0.0f;

    // warm-up: rows r0 .. r0+5
#pragma unroll
    for (int k = 0; k < 6; k++) {
        float4 x4 = *(const float4*)(xb + (size_t)(r0 + k) * W + c);
        float4 y4 = *(const float4*)(yb + (size_t)(r0 + k) * W + c);
        float xs[4] = {x4.x, x4.y, x4.z, x4.w};
        float ys[4] = {y4.x, y4.y, y4.z, y4.w};
#pragma unroll
        for (int i = 0; i < 4; i++) {
            V[0][i] += xs[i];
            V[1][i] += ys[i];
            V[2][i] = fmaf(xs[i], xs[i], V[2][i]);
            V[3][i] = fmaf(ys[i], ys[i], V[3][i]);
            V[4][i] = fmaf(xs[i], ys[i], V[4][i]);
        }
    }

    // first bottom row of the window
    float4 xn = *(const float4*)(xb + (size_t)(r0 + 6) * W + c);
    float4 yn = *(const float4*)(yb + (size_t)(r0 + 6) * W + c);

    float sacc = 0.0f;

    for (int j = 0; j < RSTRIP; j++) {
        // add bottom row (r0 + j + 6)
        {
            float xs[4] = {xn.x, xn.y, xn.z, xn.w};
            float ys[4] = {yn.x, yn.y, yn.z, yn.w};
#pragma unroll
            for (int i = 0; i < 4; i++) {
                V[0][i] += xs[i];
                V[1][i] += ys[i];
                V[2][i] = fmaf(xs[i], xs[i], V[2][i]);
                V[3][i] = fmaf(ys[i], ys[i], V[3][i]);
                V[4][i] = fmaf(xs[i], ys[i], V[4][i]);
            }
        }

        // publish V to LDS for the horizontal halo exchange
#pragma unroll
        for (int q = 0; q < 5; q++) {
            *(float4*)&ldsV[q * LSTRIDE + c] =
                make_float4(V[q][0], V[q][1], V[q][2], V[q][3]);
        }

        // prefetch: old top row (to subtract) and next bottom row — issued
        // before the barrier so latency overlaps the S computation below.
        float4 xo = *(const float4*)(xb + (size_t)(r0 + j) * W + c);
        float4 yo = *(const float4*)(yb + (size_t)(r0 + j) * W + c);
        int rn = r0 + j + 7; if (rn > HH - 1) rn = HH - 1;   // clamped, unused on last iter
        float4 xn2 = *(const float4*)(xb + (size_t)rn * W + c);
        float4 yn2 = *(const float4*)(yb + (size_t)rn * W + c);

        __syncthreads();

        // horizontal 7-sums for the 4 columns of this thread
        float Hs[5][4];
#pragma unroll
        for (int q = 0; q < 5; q++) {
            const float* P = &ldsV[q * LSTRIDE];
            float4 b = *(const float4*)(P + c + 4);   // cols c+4..c+7
            float2 e = *(const float2*)(P + c + 8);   // cols c+8, c+9
            float v0 = V[q][0], v1 = V[q][1], v2 = V[q][2], v3 = V[q][3];
            float v4 = b.x, v5 = b.y, v6 = b.z, v7 = b.w;
            float v8 = e.x, v9 = e.y;
            float h0 = ((v0 + v1) + (v2 + v3)) + ((v4 + v5) + v6);
            float h1 = h0 - v0 + v7;
            float h2 = h1 - v1 + v8;
            float h3 = h2 - v2 + v9;
            Hs[q][0] = h0; Hs[q][1] = h1; Hs[q][2] = h2; Hs[q][3] = h3;
        }

        __syncthreads();   // reads done; safe to overwrite ldsV next iteration

        // SSIM per output pixel
#pragma unroll
        for (int i = 0; i < 4; i++) {
            float ux  = Hs[0][i] * INV49;
            float uy  = Hs[1][i] * INV49;
            float uxx = Hs[2][i] * INV49;
            float uyy = Hs[3][i] * INV49;
            float uxy = Hs[4][i] * INV49;
            float uxuy = ux * uy;
            float a1 = fmaf(2.0f, uxuy, C1f);                      // 2 ux uy + C1
            float b1 = fmaf(ux, ux, fmaf(uy, uy, C1f));            // ux^2+uy^2+C1
            float vxy = COVN * (uxy - uxuy);
            float a2 = fmaf(2.0f, vxy, C2f);                       // 2 vxy + C2
            float vs  = COVN * ((uxx - ux * ux) + (uyy - uy * uy)); // vx+vy
            float b2 = vs + C2f;
            float S = (a1 * a2) / (b1 * b2);
            if (c + i < OW) sacc += S;                              // mask pad cols
        }

        // subtract top row (r0 + j)
        {
            float xs[4] = {xo.x, xo.y, xo.z, xo.w};
            float ys[4] = {yo.x, yo.y, yo.z, yo.w};
#pragma unroll
            for (int i = 0; i < 4; i++) {
                V[0][i] -= xs[i];
                V[1][i] -= ys[i];
                V[2][i] = fmaf(-xs[i], xs[i], V[2][i]);
                V[3][i] = fmaf(-ys[i], ys[i], V[3][i]);
                V[4][i] = fmaf(-xs[i], ys[i], V[4][i]);
            }
        }
        xn = xn2; yn = yn2;
    }

    // block reduction: wave shuffle -> LDS -> one double atomic per block
#pragma unroll
    for (int off = 32; off > 0; off >>= 1)
        sacc += __shfl_down(sacc, off);
    if ((t & 63) == 0) wsum[t >> 6] = sacc;
    __syncthreads();
    if (t == 0) atomicAdd(acc, (double)(wsum[0] + wsum[1]));
}

__global__ void ssim_finalize(const double* __restrict__ acc, float* __restrict__ out)
{
    out[0] = (float)(acc[0] / NPIX);
}

extern "C" void kernel_launch(void* const* d_in, const int* in_sizes, int n_in,
                              void* d_out, int out_size, void* d_ws, size_t ws_size,
                              hipStream_t stream)
{
    const float* X = (const float*)d_in[0];   // input_tensor (32,3,512,512) fp32
    const float* Y = (const float*)d_in[1];   // target       (32,3,512,512) fp32
    float* out = (float*)d_out;               // scalar fp32
    double* acc = (double*)d_ws;

    hipMemsetAsync(d_ws, 0, sizeof(double), stream);
    ssim_main<<<dim3(NSTRIP, NIMG), 128, 0, stream>>>(X, Y, acc);
    ssim_finalize<<<1, 1, 0, stream>>>(acc, out);
}

// Round 2
// 236.626 us; speedup vs baseline: 1.0287x; 1.0287x over previous
//
#include <hip/hip_runtime.h>

// SSIM (win=7, valid) fused single-pass kernel for (32,3,512,512) fp32 inputs.
// 96 images of 512x512 -> mean over 96x506x506 S map.
//
// R2: occupancy fix. 22 strips x 23 rows (was 11x46), 256-thread blocks with
// 2 cols/thread (was 128x4). Grid 2112 blocks x 4 waves = ~32 waves/CU nominal
// (was 8.25). Vertical running sums in regs, horizontal 7-sum via LDS halo.

namespace {
constexpr int W      = 512;
constexpr int HH     = 512;
constexpr int NIMG   = 96;
constexpr int OW     = 506;
constexpr int RSTRIP = 23;   // 22 * 23 = 506 output rows exactly
constexpr int NSTRIP = 22;
constexpr float C1f   = 1.0e-4f;           // (0.01*1.0)^2
constexpr float C2f   = 9.0e-4f;           // (0.03*1.0)^2
constexpr float COVN  = 49.0f / 48.0f;     // NP/(NP-1)
constexpr float INV49 = 1.0f / 49.0f;
constexpr double NPIX = 96.0 * 506.0 * 506.0;  // 24,579,456
constexpr int LSTRIDE = 520;               // plane stride: 512 + halo slack
}

__global__ __launch_bounds__(256) void ssim_main(const float* __restrict__ X,
                                                 const float* __restrict__ Y,
                                                 double* __restrict__ acc)
{
    __shared__ float ldsV[5 * LSTRIDE];
    __shared__ float wsum[4];

    const int t   = threadIdx.x;
    const int c   = t * 2;                    // this thread's 2 columns: c, c+1
    const int img = blockIdx.y;
    const int r0  = blockIdx.x * RSTRIP;      // first output row of strip

    const float* xb = X + (size_t)img * W * HH;
    const float* yb = Y + (size_t)img * W * HH;

    // running vertical sums over the 7-row window, per column:
    // V[0]=sum x, V[1]=sum y, V[2]=sum x^2, V[3]=sum y^2, V[4]=sum x*y
    float V[5][2];
#pragma unroll
    for (int q = 0; q < 5; q++)
#pragma unroll
        for (int i = 0; i < 2; i++) V[q][i] = 0.0f;

    // warm-up: rows r0 .. r0+5
#pragma unroll
    for (int k = 0; k < 6; k++) {
        float2 x2 = *(const float2*)(xb + (size_t)(r0 + k) * W + c);
        float2 y2 = *(const float2*)(yb + (size_t)(r0 + k) * W + c);
        float xs[2] = {x2.x, x2.y};
        float ys[2] = {y2.x, y2.y};
#pragma unroll
        for (int i = 0; i < 2; i++) {
            V[0][i] += xs[i];
            V[1][i] += ys[i];
            V[2][i] = fmaf(xs[i], xs[i], V[2][i]);
            V[3][i] = fmaf(ys[i], ys[i], V[3][i]);
            V[4][i] = fmaf(xs[i], ys[i], V[4][i]);
        }
    }

    // first bottom row of the window
    float2 xn = *(const float2*)(xb + (size_t)(r0 + 6) * W + c);
    float2 yn = *(const float2*)(yb + (size_t)(r0 + 6) * W + c);

    float sacc = 0.0f;

    for (int j = 0; j < RSTRIP; j++) {
        // add bottom row (r0 + j + 6)
        {
            float xs[2] = {xn.x, xn.y};
            float ys[2] = {yn.x, yn.y};
#pragma unroll
            for (int i = 0; i < 2; i++) {
                V[0][i] += xs[i];
                V[1][i] += ys[i];
                V[2][i] = fmaf(xs[i], xs[i], V[2][i]);
                V[3][i] = fmaf(ys[i], ys[i], V[3][i]);
                V[4][i] = fmaf(xs[i], ys[i], V[4][i]);
            }
        }

        // publish V to LDS for the horizontal halo exchange
#pragma unroll
        for (int q = 0; q < 5; q++) {
            *(float2*)&ldsV[q * LSTRIDE + c] = make_float2(V[q][0], V[q][1]);
        }

        // prefetch: old top row (to subtract) and next bottom row — issued
        // before the barrier so latency overlaps the S computation below.
        float2 xo = *(const float2*)(xb + (size_t)(r0 + j) * W + c);
        float2 yo = *(const float2*)(yb + (size_t)(r0 + j) * W + c);
        int rn = r0 + j + 7; if (rn > HH - 1) rn = HH - 1;   // clamped; unused on last iter
        float2 xn2 = *(const float2*)(xb + (size_t)rn * W + c);
        float2 yn2 = *(const float2*)(yb + (size_t)rn * W + c);

        __syncthreads();

        // horizontal 7-sums for this thread's 2 columns
        float Hs[5][2];
#pragma unroll
        for (int q = 0; q < 5; q++) {
            const float* P = &ldsV[q * LSTRIDE];
            float2 n1 = *(const float2*)(P + c + 2);   // cols c+2, c+3
            float2 n2 = *(const float2*)(P + c + 4);   // cols c+4, c+5
            float2 n3 = *(const float2*)(P + c + 6);   // cols c+6, c+7
            float v0 = V[q][0], v1 = V[q][1];
            float h0 = ((v0 + v1) + (n1.x + n1.y)) + ((n2.x + n2.y) + n3.x);
            float h1 = h0 - v0 + n3.y;
            Hs[q][0] = h0; Hs[q][1] = h1;
        }

        __syncthreads();   // reads done; safe to overwrite ldsV next iteration

        // SSIM per output pixel
#pragma unroll
        for (int i = 0; i < 2; i++) {
            float ux  = Hs[0][i] * INV49;
            float uy  = Hs[1][i] * INV49;
            float uxx = Hs[2][i] * INV49;
            float uyy = Hs[3][i] * INV49;
            float uxy = Hs[4][i] * INV49;
            float uxuy = ux * uy;
            float a1 = fmaf(2.0f, uxuy, C1f);                      // 2 ux uy + C1
            float b1 = fmaf(ux, ux, fmaf(uy, uy, C1f));            // ux^2+uy^2+C1
            float vxy = COVN * (uxy - uxuy);
            float a2 = fmaf(2.0f, vxy, C2f);                       // 2 vxy + C2
            float vs  = COVN * ((uxx - ux * ux) + (uyy - uy * uy)); // vx+vy
            float b2 = vs + C2f;
            float S = (a1 * a2) / (b1 * b2);
            if (c + i < OW) sacc += S;                              // mask pad cols
        }

        // subtract top row (r0 + j)
        {
            float xs[2] = {xo.x, xo.y};
            float ys[2] = {yo.x, yo.y};
#pragma unroll
            for (int i = 0; i < 2; i++) {
                V[0][i] -= xs[i];
                V[1][i] -= ys[i];
                V[2][i] = fmaf(-xs[i], xs[i], V[2][i]);
                V[3][i] = fmaf(-ys[i], ys[i], V[3][i]);
                V[4][i] = fmaf(-xs[i], ys[i], V[4][i]);
            }
        }
        xn = xn2; yn = yn2;
    }

    // block reduction: wave shuffle -> LDS -> one double atomic per block
#pragma unroll
    for (int off = 32; off > 0; off >>= 1)
        sacc += __shfl_down(sacc, off);
    if ((t & 63) == 0) wsum[t >> 6] = sacc;
    __syncthreads();
    if (t == 0) atomicAdd(acc, (double)((wsum[0] + wsum[1]) + (wsum[2] + wsum[3])));
}

__global__ void ssim_finalize(const double* __restrict__ acc, float* __restrict__ out)
{
    out[0] = (float)(acc[0] / NPIX);
}

extern "C" void kernel_launch(void* const* d_in, const int* in_sizes, int n_in,
                              void* d_out, int out_size, void* d_ws, size_t ws_size,
                              hipStream_t stream)
{
    const float* X = (const float*)d_in[0];   // input_tensor (32,3,512,512) fp32
    const float* Y = (const float*)d_in[1];   // target       (32,3,512,512) fp32
    float* out = (float*)d_out;               // scalar fp32
    double* acc = (double*)d_ws;

    hipMemsetAsync(d_ws, 0, sizeof(double), stream);
    ssim_main<<<dim3(NSTRIP, NIMG), 256, 0, stream>>>(X, Y, acc);
    ssim_finalize<<<1, 1, 0, stream>>>(acc, out);
}